// Round 19
// baseline (475.043 us; speedup 1.0000x reference)
//
#include <hip/hip_runtime.h>
#include <hip/hip_bf16.h>

#define NN 50000
#define NE 800000
#define DD 64
#define NEG 0.2f
#define NB (NN / 4)
#define EG4B ((NE / 4 + 255) / 256)

#define RFL(x) __builtin_amdgcn_readfirstlane(x)
typedef unsigned short u16;

// ---- FAT1: hist(+rank, both layers) | h1 | a2t — independent, one launch ----
__global__ __launch_bounds__(256) void k_fat1(
    const int* __restrict__ dst1, const int* __restrict__ dst2,
    int* __restrict__ cnt1, int* __restrict__ cnt2,
    int* __restrict__ rank1, int* __restrict__ rank2,
    const float* __restrict__ x, const float* __restrict__ W1,
    const float* __restrict__ a1s, const float* __restrict__ a1d,
    unsigned int* __restrict__ H1u, float* __restrict__ al1s, float* __restrict__ al1d,
    const float* __restrict__ W2, const float* __restrict__ a2s,
    const float* __restrict__ a2d, float* __restrict__ t2s, float* __restrict__ t2d) {
    const int bid = blockIdx.x;
    if (bid < EG4B) {
        // histogram + rank, 4 edges/thread/layer
        int t = bid * 256 + threadIdx.x;
        if (t < NE / 4) {
            int4 d1 = ((const int4*)dst1)[t];
            int4 d2 = ((const int4*)dst2)[t];
            int4 r1, r2;
            r1.x = atomicAdd(&cnt1[d1.x], 1); r1.y = atomicAdd(&cnt1[d1.y], 1);
            r1.z = atomicAdd(&cnt1[d1.z], 1); r1.w = atomicAdd(&cnt1[d1.w], 1);
            r2.x = atomicAdd(&cnt2[d2.x], 1); r2.y = atomicAdd(&cnt2[d2.y], 1);
            r2.z = atomicAdd(&cnt2[d2.z], 1); r2.w = atomicAdd(&cnt2[d2.w], 1);
            ((int4*)rank1)[t] = r1;
            ((int4*)rank2)[t] = r2;
        }
    } else if (bid < EG4B + NB) {
        // H1 = x @ W1 (stored as fp16 PAIRS: H1u[i][q] = dims (2q, 2q+1)), alpha1
        const int lane = threadIdx.x & 63;
        const int i = (bid - EG4B) * 4 + (threadIdx.x >> 6);
        const float xv = x[i * DD + lane];
        float h = 0.f;
#pragma unroll
        for (int j = 0; j < DD; ++j) h = fmaf(__shfl(xv, j), W1[j * DD + lane], h);
        float hlo = __shfl(h, (lane & 31) * 2);
        float hhi = __shfl(h, (lane & 31) * 2 + 1);
        if (lane < 32) {
            union { unsigned int u; _Float16 hh[2]; } pk2;
            pk2.hh[0] = (_Float16)hlo;
            pk2.hh[1] = (_Float16)hhi;
            H1u[(size_t)i * 32 + lane] = pk2.u;
        }
        float ps = h * a1s[lane], pd = h * a1d[lane];
#pragma unroll
        for (int o = 32; o; o >>= 1) { ps += __shfl_xor(ps, o); pd += __shfl_xor(pd, o); }
        if (lane == 0) { al1s[i] = ps; al1d[i] = pd; }
    } else {
        // t2s = W2 @ a2s, t2d = W2 @ a2d
        if (threadIdx.x < DD) {
            int j = threadIdx.x;
            float ss = 0.f, sd = 0.f;
#pragma unroll
            for (int d = 0; d < DD; ++d) {
                float w = W2[j * DD + d];
                ss = fmaf(w, a2s[d], ss);
                sd = fmaf(w, a2d[d], sd);
            }
            t2s[j] = ss;
            t2d[j] = sd;
        }
    }
}

__global__ __launch_bounds__(1024) void k_scan(const int* __restrict__ cnt1, int* __restrict__ off1,
                                               const int* __restrict__ cnt2, int* __restrict__ off2) {
    const int* cnt = blockIdx.x ? cnt2 : cnt1;
    int* off = blockIdx.x ? off2 : off1;
    __shared__ int lds[1024];
    const int tid = threadIdx.x;
    const int CH = (NN + 1023) / 1024;  // 49
    const int base = tid * CH;
    int s = 0;
    for (int q = 0; q < CH; ++q) {
        int idx = base + q;
        if (idx < NN) s += cnt[idx];
    }
    lds[tid] = s;
    __syncthreads();
    for (int d = 1; d < 1024; d <<= 1) {
        int v = (tid >= d) ? lds[tid - d] : 0;
        __syncthreads();
        lds[tid] += v;
        __syncthreads();
    }
    int run = tid ? lds[tid - 1] : 0;
    for (int q = 0; q < CH; ++q) {
        int idx = base + q;
        if (idx < NN) { off[idx] = run; run += cnt[idx]; }
    }
    if (tid == 1023) off[NN] = lds[1023];
}

// ---- placement for one layer: no atomics, 4 edges/thread ----
__device__ __forceinline__ void place_body(int t, const int* __restrict__ src,
                                           const int* __restrict__ dst,
                                           const int* __restrict__ off,
                                           const int* __restrict__ rank,
                                           u16* __restrict__ csr) {
    if (t < NE / 4) {
        int4 s = ((const int4*)src)[t];
        int4 d = ((const int4*)dst)[t];
        int4 r = ((const int4*)rank)[t];
        csr[off[d.x] + r.x] = (u16)s.x;
        csr[off[d.y] + r.y] = (u16)s.y;
        csr[off[d.z] + r.z] = (u16)s.z;
        csr[off[d.w] + r.w] = (u16)s.w;
    }
}

__global__ void k_place1(const int* __restrict__ src, const int* __restrict__ dst,
                         const int* __restrict__ off, const int* __restrict__ rank,
                         u16* __restrict__ csr) {
    place_body(blockIdx.x * blockDim.x + threadIdx.x, src, dst, off, rank, csr);
}

// ---- FAT2: place2 | layer1 (independent) — one launch ----
// layer1 phase B: half-wave per edge (32 lanes x uint = 2 fp16 dims/lane),
// one load instruction serves TWO edges.
__global__ __launch_bounds__(256) void k_fat2(
    const int* __restrict__ src2, const int* __restrict__ dst2,
    const int* __restrict__ off2, const int* __restrict__ rank2, u16* __restrict__ csr2,
    const int* __restrict__ off, const u16* __restrict__ csrc,
    const float* __restrict__ al1s, const float* __restrict__ al1d,
    const unsigned int* __restrict__ H1u,
    const float* __restrict__ t2s, const float* __restrict__ t2d,
    uint4* __restrict__ H2a, _Float16* __restrict__ H2b,
    float* __restrict__ al2s8, float* __restrict__ al2s9, float* __restrict__ al2d) {
    __shared__ int2 lsr[4][64];
    const int bid = blockIdx.x;
    if (bid < EG4B) {
        place_body(bid * 256 + threadIdx.x, src2, dst2, off2, rank2, csr2);
        return;
    }
    const int lane = threadIdx.x & 63;
    const int wid = threadIdx.x >> 6;
    const int half = lane >> 5;       // which edge of the pair
    const int q = lane & 31;          // dim-pair index
    const int i = (bid - EG4B) * 4 + wid;
    const int p0 = RFL(off[i]);
    const int p1 = RFL(off[i + 1]);
    const float adv = al1d[i];
    float numx[9], numy[9], den[9];
#pragma unroll
    for (int k = 0; k < 9; ++k) { numx[k] = 0.f; numy[k] = 0.f; den[k] = 0.f; }

    for (int base = p0; base < p1; base += 64) {
        int m = p1 - base; if (m > 64) m = 64;
        // phase A: one edge per lane (lanes >= m write sv=0, rv=0 -> safe mask)
        int sv = 0; float rv = 0.f;
        if (lane < m) {
            sv = csrc[base + lane];
            float z = al1s[sv] + adv;
            float c = z > 0.f ? z : NEG * z;       // leaky_relu (step-invariant)
            rv = __expf(c * (1.f / 9.f));          // w_k = rv^k
        }
        {
            float w = rv;
#pragma unroll
            for (int k = 0; k < 9; ++k) { den[k] += w; w *= rv; }
        }
        lsr[wid][lane] = make_int2(sv, __float_as_int(rv));
        asm volatile("s_waitcnt lgkmcnt(0)" ::: "memory");
        // phase B: 4 pairs (8 edges) per iteration, 4 loads in flight
        int j = 0;
        for (; j + 7 < m; j += 8) {
            int2 eA = lsr[wid][j     + half];
            int2 eB = lsr[wid][j + 2 + half];
            int2 eC = lsr[wid][j + 4 + half];
            int2 eD = lsr[wid][j + 6 + half];
            unsigned int uA = H1u[(size_t)eA.x * 32 + q];
            unsigned int uB = H1u[(size_t)eB.x * 32 + q];
            unsigned int uC = H1u[(size_t)eC.x * 32 + q];
            unsigned int uD = H1u[(size_t)eD.x * 32 + q];
            float rA = __int_as_float(eA.y), rB = __int_as_float(eB.y);
            float rC = __int_as_float(eC.y), rD = __int_as_float(eD.y);
            union { unsigned int u; _Float16 h[2]; } cA, cB, cC, cD;
            cA.u = uA; cB.u = uB; cC.u = uC; cD.u = uD;
            float hAx = (float)cA.h[0], hAy = (float)cA.h[1];
            float hBx = (float)cB.h[0], hBy = (float)cB.h[1];
            float hCx = (float)cC.h[0], hCy = (float)cC.h[1];
            float hDx = (float)cD.h[0], hDy = (float)cD.h[1];
            float wA = rA, wB = rB, wC = rC, wD = rD;
#pragma unroll
            for (int k = 0; k < 9; ++k) {
                numx[k] = fmaf(wA, hAx, numx[k]); numy[k] = fmaf(wA, hAy, numy[k]); wA *= rA;
                numx[k] = fmaf(wB, hBx, numx[k]); numy[k] = fmaf(wB, hBy, numy[k]); wB *= rB;
                numx[k] = fmaf(wC, hCx, numx[k]); numy[k] = fmaf(wC, hCy, numy[k]); wC *= rC;
                numx[k] = fmaf(wD, hDx, numx[k]); numy[k] = fmaf(wD, hDy, numy[k]); wD *= rD;
            }
        }
        for (; j < m; j += 2) {
            int2 e = lsr[wid][j + half];     // j+half >= m reads rv=0 -> no-op
            unsigned int u = H1u[(size_t)e.x * 32 + q];
            float r = __int_as_float(e.y);
            union { unsigned int uu; _Float16 h[2]; } c; c.uu = u;
            float hx = (float)c.h[0], hy = (float)c.h[1];
            float w = r;
#pragma unroll
            for (int k = 0; k < 9; ++k) {
                numx[k] = fmaf(w, hx, numx[k]); numy[k] = fmaf(w, hy, numy[k]); w *= r;
            }
        }
    }
    // combine halves (each half accumulated its own edges)
#pragma unroll
    for (int k = 0; k < 9; ++k) {
        numx[k] += __shfl_xor(numx[k], 32);
        numy[k] += __shfl_xor(numy[k], 32);
    }
    // reduce den partials across lanes
#pragma unroll
    for (int k = 0; k < 9; ++k) {
#pragma unroll
        for (int o = 32; o; o >>= 1) den[k] += __shfl_xor(den[k], o);
    }

    const float tss = t2s[lane];
    const float tdd = t2d[lane];
    float hm[9];
#pragma unroll
    for (int k = 0; k < 9; ++k) {
        // dim = lane: value lives in lane (lane>>1), component (lane&1)
        float a = __shfl(numx[k], lane >> 1);
        float b = __shfl(numy[k], lane >> 1);
        float nm = (lane & 1) ? b : a;
        float t = (float)(k + 1) * (1.f / 9.f);
        float v = (den[k] > 0.f) ? (t * nm / den[k]) : 0.f;
        hm[k] = (v > 0.f) ? v : expm1f(v);         // ELU
    }
#pragma unroll
    for (int k = 0; k < 9; ++k) {
        float ps = hm[k] * tss, pd = hm[k] * tdd;
#pragma unroll
        for (int o = 32; o; o >>= 1) { ps += __shfl_xor(ps, o); pd += __shfl_xor(pd, o); }
        if (lane == 0) {
            if (k < 8) al2s8[(size_t)i * 8 + k] = ps;
            else       al2s9[i] = ps;
            al2d[(size_t)i * 9 + k] = pd;
        }
    }
    union { _Float16 h[8]; uint4 u; } pk;
#pragma unroll
    for (int k = 0; k < 8; ++k) pk.h[k] = (_Float16)hm[k];
    H2a[(size_t)i * DD + lane] = pk.u;
    H2b[(size_t)i * DD + lane] = (_Float16)hm[8];
}

// ---- layer2: phase A -> LDS -> phase B (2-edge batches) -> one W2 matvec ----
__global__ __launch_bounds__(256) void k_l2(
    const int* __restrict__ off, const u16* __restrict__ csrc,
    const float* __restrict__ al2s8, const float* __restrict__ al2s9,
    const float* __restrict__ al2d,
    const uint4* __restrict__ H2a, const _Float16* __restrict__ H2b,
    const float* __restrict__ W2, float* __restrict__ out) {
    __shared__ float lw[4][64][12];   // [0..8]=w_k, [9]=src bits
    const int lane = threadIdx.x & 63;
    const int wid = threadIdx.x >> 6;
    const int i = blockIdx.x * 4 + wid;
    const int p0 = RFL(off[i]);
    const int p1 = RFL(off[i + 1]);
    float adv[9];
#pragma unroll
    for (int k = 0; k < 9; ++k) adv[k] = al2d[(size_t)i * 9 + k];
    float num[9], den[9];
#pragma unroll
    for (int k = 0; k < 9; ++k) { num[k] = 0.f; den[k] = 0.f; }

    for (int base = p0; base < p1; base += 64) {
        int m = p1 - base; if (m > 64) m = 64;
        int sv = 0; float wv[9];
#pragma unroll
        for (int k = 0; k < 9; ++k) wv[k] = 0.f;
        if (lane < m) {
            sv = csrc[base + lane];
            const float4* pa = (const float4*)(al2s8 + (size_t)sv * 8);
            float4 A0 = pa[0], A1 = pa[1];
            float as[9] = {A0.x, A0.y, A0.z, A0.w, A1.x, A1.y, A1.z, A1.w, al2s9[sv]};
#pragma unroll
            for (int k = 0; k < 9; ++k) {
                float z = as[k] + adv[k];
                float lr = z > 0.f ? z : NEG * z;
                wv[k] = __expf(lr);
            }
        }
#pragma unroll
        for (int k = 0; k < 9; ++k) den[k] += wv[k];
        float* dst = &lw[wid][lane][0];
        *(float4*)dst       = make_float4(wv[0], wv[1], wv[2], wv[3]);
        *(float4*)(dst + 4) = make_float4(wv[4], wv[5], wv[6], wv[7]);
        dst[8] = wv[8];
        dst[9] = __int_as_float(sv);
        asm volatile("s_waitcnt lgkmcnt(0)" ::: "memory");
        int j = 0;
        for (; j + 1 < m; j += 2) {
            const float* s0 = &lw[wid][j][0];
            const float* s1 = &lw[wid][j + 1][0];
            int sj0 = __float_as_int(s0[9]);
            int sj1 = __float_as_int(s1[9]);
            union { uint4 v; _Float16 h[8]; } c0, c1;
            c0.v = H2a[(size_t)sj0 * DD + lane];
            c1.v = H2a[(size_t)sj1 * DD + lane];
            float h90 = (float)H2b[(size_t)sj0 * DD + lane];
            float h91 = (float)H2b[(size_t)sj1 * DD + lane];
            float4 wA0 = *(const float4*)s0, wB0 = *(const float4*)(s0 + 4);
            float4 wA1 = *(const float4*)s1, wB1 = *(const float4*)(s1 + 4);
            num[0] = fmaf(wA0.x, (float)c0.h[0], num[0]);
            num[1] = fmaf(wA0.y, (float)c0.h[1], num[1]);
            num[2] = fmaf(wA0.z, (float)c0.h[2], num[2]);
            num[3] = fmaf(wA0.w, (float)c0.h[3], num[3]);
            num[4] = fmaf(wB0.x, (float)c0.h[4], num[4]);
            num[5] = fmaf(wB0.y, (float)c0.h[5], num[5]);
            num[6] = fmaf(wB0.z, (float)c0.h[6], num[6]);
            num[7] = fmaf(wB0.w, (float)c0.h[7], num[7]);
            num[8] = fmaf(s0[8], h90, num[8]);
            num[0] = fmaf(wA1.x, (float)c1.h[0], num[0]);
            num[1] = fmaf(wA1.y, (float)c1.h[1], num[1]);
            num[2] = fmaf(wA1.z, (float)c1.h[2], num[2]);
            num[3] = fmaf(wA1.w, (float)c1.h[3], num[3]);
            num[4] = fmaf(wB1.x, (float)c1.h[4], num[4]);
            num[5] = fmaf(wB1.y, (float)c1.h[5], num[5]);
            num[6] = fmaf(wB1.z, (float)c1.h[6], num[6]);
            num[7] = fmaf(wB1.w, (float)c1.h[7], num[7]);
            num[8] = fmaf(s1[8], h91, num[8]);
        }
        if (j < m) {
            const float* s0 = &lw[wid][j][0];
            int sj0 = __float_as_int(s0[9]);
            union { uint4 v; _Float16 h[8]; } c0;
            c0.v = H2a[(size_t)sj0 * DD + lane];
            float h90 = (float)H2b[(size_t)sj0 * DD + lane];
            float4 wA0 = *(const float4*)s0, wB0 = *(const float4*)(s0 + 4);
            num[0] = fmaf(wA0.x, (float)c0.h[0], num[0]);
            num[1] = fmaf(wA0.y, (float)c0.h[1], num[1]);
            num[2] = fmaf(wA0.z, (float)c0.h[2], num[2]);
            num[3] = fmaf(wA0.w, (float)c0.h[3], num[3]);
            num[4] = fmaf(wB0.x, (float)c0.h[4], num[4]);
            num[5] = fmaf(wB0.y, (float)c0.h[5], num[5]);
            num[6] = fmaf(wB0.z, (float)c0.h[6], num[6]);
            num[7] = fmaf(wB0.w, (float)c0.h[7], num[7]);
            num[8] = fmaf(s0[8], h90, num[8]);
        }
    }
#pragma unroll
    for (int k = 0; k < 9; ++k) {
#pragma unroll
        for (int o = 32; o; o >>= 1) den[k] += __shfl_xor(den[k], o);
    }
    float vsum = 0.f;
#pragma unroll
    for (int k = 0; k < 9; ++k) vsum += (den[k] > 0.f) ? (num[k] / den[k]) : 0.f;
    float h2 = 0.f;
#pragma unroll 8
    for (int j = 0; j < DD; ++j) h2 = fmaf(__shfl(vsum, j), W2[j * DD + lane], h2);
    out[(size_t)i * DD + lane] = h2 * (1.f / 9.f);
}

extern "C" void kernel_launch(void* const* d_in, const int* in_sizes, int n_in,
                              void* d_out, int out_size, void* d_ws, size_t ws_size,
                              hipStream_t stream) {
    const float* x   = (const float*)d_in[0];
    const int*   ei1 = (const int*)d_in[1];
    const int*   ei2 = (const int*)d_in[2];
    const float* W1  = (const float*)d_in[3];
    const float* a1s = (const float*)d_in[4];
    const float* a1d = (const float*)d_in[5];
    const float* W2  = (const float*)d_in[6];
    const float* a2s = (const float*)d_in[7];
    const float* a2d = (const float*)d_in[8];
    float* out = (float*)d_out;

    const int* src1 = ei1;
    const int* dst1 = ei1 + NE;
    const int* src2 = ei2;
    const int* dst2 = ei2 + NE;

    // ---- workspace layout (4-byte words), ~77.6 MB total ----
    uint4* H2a    = (uint4*)d_ws;                           // NN*64 uint4 (NN*256 words)
    unsigned int* H1u = (unsigned int*)((float*)d_ws + (size_t)NN * 256); // NN*32 uints
    float* al1s   = (float*)H1u + (size_t)NN * 32;          // NN   (FIX: was NN*16 — overlapped H1u)
    float* al1d   = al1s + NN;                              // NN
    float* al2s8  = al1d + NN;                              // NN*8
    float* al2s9  = al2s8 + (size_t)NN * 8;                 // NN
    float* al2d   = al2s9 + NN;                             // NN*9
    _Float16* H2b = (_Float16*)(al2d + (size_t)NN * 9);     // NN*DD halves
    int* rank1 = (int*)((float*)H2b + (size_t)NN * DD / 2); // NE
    int* rank2 = rank1 + NE;                                // NE
    u16* csr1  = (u16*)(rank2 + NE);                        // NE ushorts
    u16* csr2  = csr1 + NE;                                 // NE ushorts
    float* t2s = (float*)(csr2 + NE);                       // 64
    float* t2d = t2s + DD;                                  // 64
    int* off1 = (int*)(t2d + DD);                           // NN+1
    int* off2 = off1 + (NN + 1);                            // NN+1
    int* cnt1 = off2 + (NN + 1);                            // NN
    int* cnt2 = cnt1 + NN;                                  // NN (contiguous with cnt1)

    hipMemsetAsync(cnt1, 0, 2 * NN * sizeof(int), stream);
    k_fat1<<<EG4B + NB + 1, 256, 0, stream>>>(
        dst1, dst2, cnt1, cnt2, rank1, rank2,
        x, W1, a1s, a1d, H1u, al1s, al1d,
        W2, a2s, a2d, t2s, t2d);
    k_scan<<<2, 1024, 0, stream>>>(cnt1, off1, cnt2, off2);
    k_place1<<<EG4B, 256, 0, stream>>>(src1, dst1, off1, rank1, csr1);
    k_fat2<<<EG4B + NB, 256, 0, stream>>>(
        src2, dst2, off2, rank2, csr2,
        off1, csr1, al1s, al1d, H1u, t2s, t2d,
        H2a, H2b, al2s8, al2s9, al2d);
    k_l2<<<NB, 256, 0, stream>>>(off2, csr2, al2s8, al2s9, al2d, H2a, H2b, W2, out);
}

// Round 20
// 457.719 us; speedup vs baseline: 1.0378x; 1.0378x over previous
//
#include <hip/hip_runtime.h>
#include <hip/hip_bf16.h>

#define NN 50000
#define NE 800000
#define DD 64
#define NEG 0.2f
#define NB (NN / 4)
#define EG4B ((NE / 4 + 255) / 256)

#define RFL(x) __builtin_amdgcn_readfirstlane(x)
typedef unsigned short u16;

// ---- FAT1: hist(+rank, both layers) | h1 | a2t — independent, one launch ----
__global__ __launch_bounds__(256) void k_fat1(
    const int* __restrict__ dst1, const int* __restrict__ dst2,
    int* __restrict__ cnt1, int* __restrict__ cnt2,
    int* __restrict__ rank1, int* __restrict__ rank2,
    const float* __restrict__ x, const float* __restrict__ W1,
    const float* __restrict__ a1s, const float* __restrict__ a1d,
    _Float16* __restrict__ H1h, float* __restrict__ al1s, float* __restrict__ al1d,
    const float* __restrict__ W2, const float* __restrict__ a2s,
    const float* __restrict__ a2d, float* __restrict__ t2s, float* __restrict__ t2d) {
    const int bid = blockIdx.x;
    if (bid < EG4B) {
        // histogram + rank, 4 edges/thread/layer
        int t = bid * 256 + threadIdx.x;
        if (t < NE / 4) {
            int4 d1 = ((const int4*)dst1)[t];
            int4 d2 = ((const int4*)dst2)[t];
            int4 r1, r2;
            r1.x = atomicAdd(&cnt1[d1.x], 1); r1.y = atomicAdd(&cnt1[d1.y], 1);
            r1.z = atomicAdd(&cnt1[d1.z], 1); r1.w = atomicAdd(&cnt1[d1.w], 1);
            r2.x = atomicAdd(&cnt2[d2.x], 1); r2.y = atomicAdd(&cnt2[d2.y], 1);
            r2.z = atomicAdd(&cnt2[d2.z], 1); r2.w = atomicAdd(&cnt2[d2.w], 1);
            ((int4*)rank1)[t] = r1;
            ((int4*)rank2)[t] = r2;
        }
    } else if (bid < EG4B + NB) {
        // H1 = x @ W1 (stored fp16), alpha1 reductions
        const int lane = threadIdx.x & 63;
        const int i = (bid - EG4B) * 4 + (threadIdx.x >> 6);
        const float xv = x[i * DD + lane];
        float h = 0.f;
#pragma unroll
        for (int j = 0; j < DD; ++j) h = fmaf(__shfl(xv, j), W1[j * DD + lane], h);
        H1h[(size_t)i * DD + lane] = (_Float16)h;
        float ps = h * a1s[lane], pd = h * a1d[lane];
#pragma unroll
        for (int o = 32; o; o >>= 1) { ps += __shfl_xor(ps, o); pd += __shfl_xor(pd, o); }
        if (lane == 0) { al1s[i] = ps; al1d[i] = pd; }
    } else {
        // t2s = W2 @ a2s, t2d = W2 @ a2d
        if (threadIdx.x < DD) {
            int j = threadIdx.x;
            float ss = 0.f, sd = 0.f;
#pragma unroll
            for (int d = 0; d < DD; ++d) {
                float w = W2[j * DD + d];
                ss = fmaf(w, a2s[d], ss);
                sd = fmaf(w, a2d[d], sd);
            }
            t2s[j] = ss;
            t2d[j] = sd;
        }
    }
}

__global__ __launch_bounds__(1024) void k_scan(const int* __restrict__ cnt1, int* __restrict__ off1,
                                               const int* __restrict__ cnt2, int* __restrict__ off2) {
    const int* cnt = blockIdx.x ? cnt2 : cnt1;
    int* off = blockIdx.x ? off2 : off1;
    __shared__ int lds[1024];
    const int tid = threadIdx.x;
    const int CH = (NN + 1023) / 1024;  // 49
    const int base = tid * CH;
    int s = 0;
    for (int q = 0; q < CH; ++q) {
        int idx = base + q;
        if (idx < NN) s += cnt[idx];
    }
    lds[tid] = s;
    __syncthreads();
    for (int d = 1; d < 1024; d <<= 1) {
        int v = (tid >= d) ? lds[tid - d] : 0;
        __syncthreads();
        lds[tid] += v;
        __syncthreads();
    }
    int run = tid ? lds[tid - 1] : 0;
    for (int q = 0; q < CH; ++q) {
        int idx = base + q;
        if (idx < NN) { off[idx] = run; run += cnt[idx]; }
    }
    if (tid == 1023) off[NN] = lds[1023];
}

// ---- placement for one layer: no atomics, 4 edges/thread ----
__device__ __forceinline__ void place_body(int t, const int* __restrict__ src,
                                           const int* __restrict__ dst,
                                           const int* __restrict__ off,
                                           const int* __restrict__ rank,
                                           u16* __restrict__ csr) {
    if (t < NE / 4) {
        int4 s = ((const int4*)src)[t];
        int4 d = ((const int4*)dst)[t];
        int4 r = ((const int4*)rank)[t];
        csr[off[d.x] + r.x] = (u16)s.x;
        csr[off[d.y] + r.y] = (u16)s.y;
        csr[off[d.z] + r.z] = (u16)s.z;
        csr[off[d.w] + r.w] = (u16)s.w;
    }
}

__global__ void k_place1(const int* __restrict__ src, const int* __restrict__ dst,
                         const int* __restrict__ off, const int* __restrict__ rank,
                         u16* __restrict__ csr) {
    place_body(blockIdx.x * blockDim.x + threadIdx.x, src, dst, off, rank, csr);
}

// ---- FAT2: place2 | layer1 (independent) — one launch ----
__global__ __launch_bounds__(256) void k_fat2(
    const int* __restrict__ src2, const int* __restrict__ dst2,
    const int* __restrict__ off2, const int* __restrict__ rank2, u16* __restrict__ csr2,
    const int* __restrict__ off, const u16* __restrict__ csrc,
    const float* __restrict__ al1s, const float* __restrict__ al1d,
    const _Float16* __restrict__ H1h,
    const float* __restrict__ t2s, const float* __restrict__ t2d,
    uint4* __restrict__ H2a, _Float16* __restrict__ H2b,
    float* __restrict__ al2s8, float* __restrict__ al2s9, float* __restrict__ al2d) {
    __shared__ int2 lsr[4][64];
    const int bid = blockIdx.x;
    if (bid < EG4B) {
        place_body(bid * 256 + threadIdx.x, src2, dst2, off2, rank2, csr2);
        return;
    }
    // ---- layer1: phase A (parallel score+den) -> LDS -> phase B (4 fp16 gathers) ----
    const int lane = threadIdx.x & 63;
    const int wid = threadIdx.x >> 6;
    const int i = (bid - EG4B) * 4 + wid;
    const int p0 = RFL(off[i]);
    const int p1 = RFL(off[i + 1]);
    const float adv = al1d[i];
    float num[9], den[9];
#pragma unroll
    for (int k = 0; k < 9; ++k) { num[k] = 0.f; den[k] = 0.f; }

    for (int base = p0; base < p1; base += 64) {
        int m = p1 - base; if (m > 64) m = 64;
        int sv = 0; float rv = 0.f;
        if (lane < m) {
            sv = csrc[base + lane];
            float z = al1s[sv] + adv;
            float c = z > 0.f ? z : NEG * z;       // leaky_relu (step-invariant)
            rv = __expf(c * (1.f / 9.f));          // w_k = rv^k
        }
        {
            float w = rv;
#pragma unroll
            for (int k = 0; k < 9; ++k) { den[k] += w; w *= rv; }
        }
        lsr[wid][lane] = make_int2(sv, __float_as_int(rv));
        asm volatile("s_waitcnt lgkmcnt(0)" ::: "memory");
        int j = 0;
        for (; j + 3 < m; j += 4) {
            int2 e0 = lsr[wid][j], e1 = lsr[wid][j + 1];
            int2 e2 = lsr[wid][j + 2], e3 = lsr[wid][j + 3];
            float h0 = (float)H1h[(size_t)e0.x * DD + lane];
            float h1v = (float)H1h[(size_t)e1.x * DD + lane];
            float h2v = (float)H1h[(size_t)e2.x * DD + lane];
            float h3v = (float)H1h[(size_t)e3.x * DD + lane];
            float r0 = __int_as_float(e0.y), r1 = __int_as_float(e1.y);
            float r2 = __int_as_float(e2.y), r3 = __int_as_float(e3.y);
            float w0 = r0, w1 = r1, w2 = r2, w3 = r3;
#pragma unroll
            for (int k = 0; k < 9; ++k) {
                num[k] = fmaf(w0, h0, num[k]);  w0 *= r0;
                num[k] = fmaf(w1, h1v, num[k]); w1 *= r1;
                num[k] = fmaf(w2, h2v, num[k]); w2 *= r2;
                num[k] = fmaf(w3, h3v, num[k]); w3 *= r3;
            }
        }
        for (; j < m; ++j) {
            int2 e0 = lsr[wid][j];
            float h0 = (float)H1h[(size_t)e0.x * DD + lane];
            float r0 = __int_as_float(e0.y);
            float w0 = r0;
#pragma unroll
            for (int k = 0; k < 9; ++k) { num[k] = fmaf(w0, h0, num[k]); w0 *= r0; }
        }
    }
#pragma unroll
    for (int k = 0; k < 9; ++k) {
#pragma unroll
        for (int o = 32; o; o >>= 1) den[k] += __shfl_xor(den[k], o);
    }

    const float tss = t2s[lane];
    const float tdd = t2d[lane];
    float hm[9];
#pragma unroll
    for (int k = 0; k < 9; ++k) {
        float t = (float)(k + 1) * (1.f / 9.f);
        float v = (den[k] > 0.f) ? (t * num[k] / den[k]) : 0.f;
        hm[k] = (v > 0.f) ? v : expm1f(v);         // ELU
    }
#pragma unroll
    for (int k = 0; k < 9; ++k) {
        float ps = hm[k] * tss, pd = hm[k] * tdd;
#pragma unroll
        for (int o = 32; o; o >>= 1) { ps += __shfl_xor(ps, o); pd += __shfl_xor(pd, o); }
        if (lane == 0) {
            if (k < 8) al2s8[(size_t)i * 8 + k] = ps;
            else       al2s9[i] = ps;
            al2d[(size_t)i * 9 + k] = pd;
        }
    }
    union { _Float16 h[8]; uint4 u; } pk;
#pragma unroll
    for (int k = 0; k < 8; ++k) pk.h[k] = (_Float16)hm[k];
    H2a[(size_t)i * DD + lane] = pk.u;
    H2b[(size_t)i * DD + lane] = (_Float16)hm[8];
}

// ---- layer2: phase A -> LDS -> phase B (2-edge batches) -> one W2 matvec ----
__global__ __launch_bounds__(256) void k_l2(
    const int* __restrict__ off, const u16* __restrict__ csrc,
    const float* __restrict__ al2s8, const float* __restrict__ al2s9,
    const float* __restrict__ al2d,
    const uint4* __restrict__ H2a, const _Float16* __restrict__ H2b,
    const float* __restrict__ W2, float* __restrict__ out) {
    __shared__ float lw[4][64][12];   // [0..8]=w_k, [9]=src bits
    const int lane = threadIdx.x & 63;
    const int wid = threadIdx.x >> 6;
    const int i = blockIdx.x * 4 + wid;
    const int p0 = RFL(off[i]);
    const int p1 = RFL(off[i + 1]);
    float adv[9];
#pragma unroll
    for (int k = 0; k < 9; ++k) adv[k] = al2d[(size_t)i * 9 + k];
    float num[9], den[9];
#pragma unroll
    for (int k = 0; k < 9; ++k) { num[k] = 0.f; den[k] = 0.f; }

    for (int base = p0; base < p1; base += 64) {
        int m = p1 - base; if (m > 64) m = 64;
        int sv = 0; float wv[9];
#pragma unroll
        for (int k = 0; k < 9; ++k) wv[k] = 0.f;
        if (lane < m) {
            sv = csrc[base + lane];
            const float4* pa = (const float4*)(al2s8 + (size_t)sv * 8);
            float4 A0 = pa[0], A1 = pa[1];
            float as[9] = {A0.x, A0.y, A0.z, A0.w, A1.x, A1.y, A1.z, A1.w, al2s9[sv]};
#pragma unroll
            for (int k = 0; k < 9; ++k) {
                float z = as[k] + adv[k];
                float lr = z > 0.f ? z : NEG * z;
                wv[k] = __expf(lr);
            }
        }
#pragma unroll
        for (int k = 0; k < 9; ++k) den[k] += wv[k];
        float* dst = &lw[wid][lane][0];
        *(float4*)dst       = make_float4(wv[0], wv[1], wv[2], wv[3]);
        *(float4*)(dst + 4) = make_float4(wv[4], wv[5], wv[6], wv[7]);
        dst[8] = wv[8];
        dst[9] = __int_as_float(sv);
        asm volatile("s_waitcnt lgkmcnt(0)" ::: "memory");
        int j = 0;
        for (; j + 1 < m; j += 2) {
            const float* s0 = &lw[wid][j][0];
            const float* s1 = &lw[wid][j + 1][0];
            int sj0 = __float_as_int(s0[9]);
            int sj1 = __float_as_int(s1[9]);
            union { uint4 v; _Float16 h[8]; } c0, c1;
            c0.v = H2a[(size_t)sj0 * DD + lane];
            c1.v = H2a[(size_t)sj1 * DD + lane];
            float h90 = (float)H2b[(size_t)sj0 * DD + lane];
            float h91 = (float)H2b[(size_t)sj1 * DD + lane];
            float4 wA0 = *(const float4*)s0, wB0 = *(const float4*)(s0 + 4);
            float4 wA1 = *(const float4*)s1, wB1 = *(const float4*)(s1 + 4);
            num[0] = fmaf(wA0.x, (float)c0.h[0], num[0]);
            num[1] = fmaf(wA0.y, (float)c0.h[1], num[1]);
            num[2] = fmaf(wA0.z, (float)c0.h[2], num[2]);
            num[3] = fmaf(wA0.w, (float)c0.h[3], num[3]);
            num[4] = fmaf(wB0.x, (float)c0.h[4], num[4]);
            num[5] = fmaf(wB0.y, (float)c0.h[5], num[5]);
            num[6] = fmaf(wB0.z, (float)c0.h[6], num[6]);
            num[7] = fmaf(wB0.w, (float)c0.h[7], num[7]);
            num[8] = fmaf(s0[8], h90, num[8]);
            num[0] = fmaf(wA1.x, (float)c1.h[0], num[0]);
            num[1] = fmaf(wA1.y, (float)c1.h[1], num[1]);
            num[2] = fmaf(wA1.z, (float)c1.h[2], num[2]);
            num[3] = fmaf(wA1.w, (float)c1.h[3], num[3]);
            num[4] = fmaf(wB1.x, (float)c1.h[4], num[4]);
            num[5] = fmaf(wB1.y, (float)c1.h[5], num[5]);
            num[6] = fmaf(wB1.z, (float)c1.h[6], num[6]);
            num[7] = fmaf(wB1.w, (float)c1.h[7], num[7]);
            num[8] = fmaf(s1[8], h91, num[8]);
        }
        if (j < m) {
            const float* s0 = &lw[wid][j][0];
            int sj0 = __float_as_int(s0[9]);
            union { uint4 v; _Float16 h[8]; } c0;
            c0.v = H2a[(size_t)sj0 * DD + lane];
            float h90 = (float)H2b[(size_t)sj0 * DD + lane];
            float4 wA0 = *(const float4*)s0, wB0 = *(const float4*)(s0 + 4);
            num[0] = fmaf(wA0.x, (float)c0.h[0], num[0]);
            num[1] = fmaf(wA0.y, (float)c0.h[1], num[1]);
            num[2] = fmaf(wA0.z, (float)c0.h[2], num[2]);
            num[3] = fmaf(wA0.w, (float)c0.h[3], num[3]);
            num[4] = fmaf(wB0.x, (float)c0.h[4], num[4]);
            num[5] = fmaf(wB0.y, (float)c0.h[5], num[5]);
            num[6] = fmaf(wB0.z, (float)c0.h[6], num[6]);
            num[7] = fmaf(wB0.w, (float)c0.h[7], num[7]);
            num[8] = fmaf(s0[8], h90, num[8]);
        }
    }
#pragma unroll
    for (int k = 0; k < 9; ++k) {
#pragma unroll
        for (int o = 32; o; o >>= 1) den[k] += __shfl_xor(den[k], o);
    }
    float vsum = 0.f;
#pragma unroll
    for (int k = 0; k < 9; ++k) vsum += (den[k] > 0.f) ? (num[k] / den[k]) : 0.f;
    float h2 = 0.f;
#pragma unroll 8
    for (int j = 0; j < DD; ++j) h2 = fmaf(__shfl(vsum, j), W2[j * DD + lane], h2);
    out[(size_t)i * DD + lane] = h2 * (1.f / 9.f);
}

extern "C" void kernel_launch(void* const* d_in, const int* in_sizes, int n_in,
                              void* d_out, int out_size, void* d_ws, size_t ws_size,
                              hipStream_t stream) {
    const float* x   = (const float*)d_in[0];
    const int*   ei1 = (const int*)d_in[1];
    const int*   ei2 = (const int*)d_in[2];
    const float* W1  = (const float*)d_in[3];
    const float* a1s = (const float*)d_in[4];
    const float* a1d = (const float*)d_in[5];
    const float* W2  = (const float*)d_in[6];
    const float* a2s = (const float*)d_in[7];
    const float* a2d = (const float*)d_in[8];
    float* out = (float*)d_out;

    const int* src1 = ei1;
    const int* dst1 = ei1 + NE;
    const int* src2 = ei2;
    const int* dst2 = ei2 + NE;

    // ---- workspace layout (4-byte words), ~78.4 MB total ----
    uint4* H2a    = (uint4*)d_ws;                           // NN*64 uint4
    _Float16* H1h = (_Float16*)((float*)d_ws + (size_t)NN * 256); // NN*DD halves
    float* al1s   = (float*)H1h + (size_t)NN * DD / 2;      // NN
    float* al1d   = al1s + NN;                              // NN
    float* al2s8  = al1d + NN;                              // NN*8
    float* al2s9  = al2s8 + (size_t)NN * 8;                 // NN
    float* al2d   = al2s9 + NN;                             // NN*9
    _Float16* H2b = (_Float16*)(al2d + (size_t)NN * 9);     // NN*DD halves
    int* rank1 = (int*)((float*)H2b + (size_t)NN * DD / 2); // NE
    int* rank2 = rank1 + NE;                                // NE
    u16* csr1  = (u16*)(rank2 + NE);                        // NE ushorts
    u16* csr2  = csr1 + NE;                                 // NE ushorts
    float* t2s = (float*)(csr2 + NE);                       // 64
    float* t2d = t2s + DD;                                  // 64
    int* off1 = (int*)(t2d + DD);                           // NN+1
    int* off2 = off1 + (NN + 1);                            // NN+1
    int* cnt1 = off2 + (NN + 1);                            // NN
    int* cnt2 = cnt1 + NN;                                  // NN (contiguous with cnt1)

    hipMemsetAsync(cnt1, 0, 2 * NN * sizeof(int), stream);
    k_fat1<<<EG4B + NB + 1, 256, 0, stream>>>(
        dst1, dst2, cnt1, cnt2, rank1, rank2,
        x, W1, a1s, a1d, H1h, al1s, al1d,
        W2, a2s, a2d, t2s, t2d);
    k_scan<<<2, 1024, 0, stream>>>(cnt1, off1, cnt2, off2);
    k_place1<<<EG4B, 256, 0, stream>>>(src1, dst1, off1, rank1, csr1);
    k_fat2<<<EG4B + NB, 256, 0, stream>>>(
        src2, dst2, off2, rank2, csr2,
        off1, csr1, al1s, al1d, H1h, t2s, t2d,
        H2a, H2b, al2s8, al2s9, al2d);
    k_l2<<<NB, 256, 0, stream>>>(off2, csr2, al2s8, al2s9, al2d, H2a, H2b, W2, out);
}